// Round 5
// baseline (97.189 us; speedup 1.0000x reference)
//
#include <hip/hip_runtime.h>
#include <math.h>

#define BATCH 8
#define NPRED 8192
#define MPART 2048
#define NPTS  (BATCH * NPRED)      // 65536 queries
#define QPL   4                    // queries per lane
#define SPLIT 16                   // 16 waves = 16 M-splits per block
#define PTS_PER_SPLIT (MPART / SPLIT)   // 128
#define GPS   (PTS_PER_SPLIT / 4)       // 32 groups of 4 points per split
#define QPB   256                  // queries per block (4 qpl * 64 lanes)
#define NBLK  (NPTS / QPB)         // 256 blocks (1 per CU)
#define BASE_ALPHA 0.05f
#define EPS 1e-6f

__device__ __forceinline__ unsigned long long shflx_u64(unsigned long long v, int m) {
    unsigned lo = (unsigned)v, hi = (unsigned)(v >> 32);
    lo = (unsigned)__shfl_xor((int)lo, m, 64);
    hi = (unsigned)__shfl_xor((int)hi, m, 64);
    return ((unsigned long long)hi << 32) | lo;
}

// Block = 1024 threads = 16 waves. Wave w scans M-split w (128 pts) for the
// block's 256 queries (4 per lane). Each block builds its batch's grouped-SoA
// P' tile in LDS from raw partial (bit-identical ops to the old prep_kernel).
// Scan: 2-deep register prefetch over broadcast ds_read_b128 (proven r0/r4
// mechanism; readlane/s_load variants measured slower in r1/r3).
// Grouped argmin: loop tracks (group-min, group-id); epilogue recomputes the
// winning group's 4 dots with IDENTICAL fp ops (bit-exact) to recover the
// element index; strict '<' + lowest-c tie-break = first-occurrence.
// Keys land in the (dead) staging scratch; merge uses all 16 waves (u64 min
// is commutative -> bit-identical to serial merge).
// FUSE: previous iteration's blend in the prologue; nearest gathered from
// GLOBAL partial (L2-hot, VMEM pipe) — r4's LDS gather was a random-address
// bank-conflict burst; bytes are identical (raw x,y,z == -0.5f*(-2x) exact),
// and being LDS-independent it overlaps the staging barrier wait.
template <bool FUSE>
__global__ __launch_bounds__(1024, 4) void nn_kernel(
    const float* __restrict__ src,      // [B,N,3] base positions
    const float* __restrict__ partial,  // [B,M,3] raw partial
    const float* md_in, const int* idx_in,   // FUSE only (alias outputs)
    const float* __restrict__ bmax_in,  // [NBLK] per-block max from prev pass
    float* __restrict__ refined_out,    // [B,N,3] (FUSE)
    float* md_out, int* idx_out,        // [B*N]
    float* __restrict__ bmax_out)       // [NBLK]
{
    __shared__ float4 tileP[2048];                 // 32 KB grouped-SoA P'
    __shared__ unsigned long long lk[SPLIT * QPB]; // 32 KB scratch -> keys
    __shared__ float smax[SPLIT];

    const int qb   = blockIdx.x;
    const int b    = qb >> 5;               // 32 blocks per batch
    const int tid  = threadIdx.x;
    const int wave = tid >> 6, lane = tid & 63;
    const int split = wave;

    // ---- stage raw partial (24 KB, coalesced float4) into lk scratch ----
    {
        float4* raws = (float4*)lk;
        const float4* psrc = (const float4*)(partial + (size_t)b * MPART * 3);
        raws[tid] = psrc[tid];
        if (tid < 512) raws[tid + 1024] = psrc[tid + 1024];
    }

    // ---- query prologue (global-only; overlaps the staging barrier) ----
    float axq[QPL], ayq[QPL], azq[QPL], a2q[QPL];
    if (FUSE) {
        float v = bmax_in[(b << 5) + (lane & 31)];
        #pragma unroll
        for (int o = 32; o > 0; o >>= 1) v = fmaxf(v, __shfl_down(v, o, 64));
        const float maxv = __shfl(v, 0, 64);
        const float* pbase = partial + (size_t)b * MPART * 3;
        #pragma unroll
        for (int j = 0; j < QPL; ++j) {
            const int t = (qb << 8) + (j << 6) + lane;
            const float md = md_in[t];
            const int   id = idx_in[t];
            const float alpha = BASE_ALPHA * (2.0f - md / (maxv + EPS));
            const float* nbp = pbase + 3u * (unsigned)id;   // L2-hot gather
            const float nbx = nbp[0], nby = nbp[1], nbz = nbp[2];
            const float* p = src + 3u * (unsigned)t;
            const float px = p[0], py = p[1], pz = p[2];
            axq[j] = fmaf(alpha, nbx - px, px);
            ayq[j] = fmaf(alpha, nby - py, py);
            azq[j] = fmaf(alpha, nbz - pz, pz);
            if (split == 0) {               // one copy of refined-1 to ws
                float* o = refined_out + 3u * (unsigned)t;
                o[0] = axq[j]; o[1] = ayq[j]; o[2] = azq[j];
            }
        }
    } else {
        #pragma unroll
        for (int j = 0; j < QPL; ++j) {
            const int t = (qb << 8) + (j << 6) + lane;
            const float* p = src + 3u * (unsigned)t;
            axq[j] = p[0]; ayq[j] = p[1]; azq[j] = p[2];
        }
    }
    #pragma unroll
    for (int j = 0; j < QPL; ++j)
        a2q[j] = fmaf(axq[j], axq[j], fmaf(ayq[j], ayq[j], azq[j] * azq[j]));

    __syncthreads();   // staging complete

    // ---- build grouped-SoA P' tile (identical FP ops to old prep_kernel) --
    {
        const float* rf = (const float*)lk;
        float* tpf = (float*)tileP;
        #pragma unroll
        for (int k = 0; k < 2; ++k) {
            const int m = tid + (k << 10);
            const float x = rf[3 * m], y = rf[3 * m + 1], z = rf[3 * m + 2];
            const int g = m >> 2, c = m & 3;
            float* basep = tpf + g * 16 + c;
            basep[0]  = -2.0f * x;
            basep[4]  = -2.0f * y;
            basep[8]  = -2.0f * z;
            basep[12] = fmaf(x, x, fmaf(y, y, z * z));
        }
    }
    __syncthreads();   // tile ready; raw scratch in lk is now dead

    // ---- scan: 2-deep register prefetch over broadcast b128 reads ----
    const float4* wp = tileP + split * (GPS * 4);
    float best[QPL]; int bg[QPL];
    #pragma unroll
    for (int j = 0; j < QPL; ++j) { best[j] = 1e30f; bg[j] = 0; }

    auto step = [&](int i, const float4& X, const float4& Y,
                    const float4& Z, const float4& W) {
        #pragma unroll
        for (int j = 0; j < QPL; ++j) {
            const float ax = axq[j], ay = ayq[j], az = azq[j];
            const float d0 = fmaf(Z.x, az, fmaf(Y.x, ay, X.x * ax)) + W.x;
            const float d1 = fmaf(Z.y, az, fmaf(Y.y, ay, X.y * ax)) + W.y;
            const float d2 = fmaf(Z.z, az, fmaf(Y.z, ay, X.z * ax)) + W.z;
            const float d3 = fmaf(Z.w, az, fmaf(Y.w, ay, X.w * ax)) + W.w;
            const float gm = fminf(fminf(fminf(d0, d1), d2), d3);
            if (gm < best[j]) bg[j] = i;       // strict <: earliest group wins
            best[j] = fminf(best[j], gm);
        }
    };

    float4 Xc = wp[0], Yc = wp[1], Zc = wp[2], Wc = wp[3];
    #pragma unroll 4
    for (int i = 0; i < GPS - 1; ++i) {
        const float4 Xn = wp[4 * i + 4];
        const float4 Yn = wp[4 * i + 5];
        const float4 Zn = wp[4 * i + 6];
        const float4 Wn = wp[4 * i + 7];
        step(i, Xc, Yc, Zc, Wc);
        Xc = Xn; Yc = Yn; Zc = Zn; Wc = Wn;
    }
    step(GPS - 1, Xc, Yc, Zc, Wc);

    // ---- epilogue: bit-exact recompute of winning group -> element index --
    unsigned long long key[QPL];
    #pragma unroll
    for (int j = 0; j < QPL; ++j) {
        const int gi = bg[j];
        const float4 X = wp[4 * gi + 0];
        const float4 Y = wp[4 * gi + 1];
        const float4 Z = wp[4 * gi + 2];
        const float4 W = wp[4 * gi + 3];
        const float ax = axq[j], ay = ayq[j], az = azq[j];
        const float d0 = fmaf(Z.x, az, fmaf(Y.x, ay, X.x * ax)) + W.x;
        const float d1 = fmaf(Z.y, az, fmaf(Y.y, ay, X.y * ax)) + W.y;
        const float d2 = fmaf(Z.z, az, fmaf(Y.z, ay, X.z * ax)) + W.z;
        const float bv = best[j];
        int c;
        if      (d0 == bv) c = 0;
        else if (d1 == bv) c = 1;
        else if (d2 == bv) c = 2;
        else               c = 3;
        const int m = (split << 7) + (gi << 2) + c;   // index within batch
        const float dd = fmaxf(bv + a2q[j], 0.0f);    // nonneg -> uint-ordered
        key[j] = ((unsigned long long)__float_as_uint(dd) << 32) | (unsigned)m;
    }

    // Keys go to lk (scratch is dead): no pre-write barrier needed.
    #pragma unroll
    for (int j = 0; j < QPL; ++j)
        lk[split * QPB + (j << 6) + lane] = key[j];
    __syncthreads();

    // ---- merge across splits, all 16 waves; u64 min == lexicographic ----
    {
        const int q  = (wave << 4) + (lane & 15);   // this lane's query
        const int s0 = (lane >> 4) << 2;            // its 4-split slice
        unsigned long long kk = lk[s0 * QPB + q];
        #pragma unroll
        for (int s = 1; s < 4; ++s) {
            const unsigned long long k = lk[(s0 + s) * QPB + q];
            if (k < kk) kk = k;
        }
        unsigned long long o = shflx_u64(kk, 16);
        if (o < kk) kk = o;
        o = shflx_u64(kk, 32);
        if (o < kk) kk = o;
        const float md = sqrtf(__uint_as_float((unsigned)(kk >> 32)));
        if (lane < 16) {
            const int t2 = (qb << 8) + q;
            md_out[t2]  = md;
            idx_out[t2] = (int)(kk & 0xffffffffu);
        }
        float w = md;
        #pragma unroll
        for (int o2 = 8; o2 > 0; o2 >>= 1) w = fmaxf(w, __shfl_xor(w, o2, 64));
        if (lane == 0) smax[wave] = w;
    }
    __syncthreads();
    if (tid == 0) {
        float m0 = smax[0];
        #pragma unroll
        for (int s = 1; s < SPLIT; ++s) m0 = fmaxf(m0, smax[s]);
        bmax_out[qb] = m0;
    }
}

// Final blend: out = refined1 + alpha2*(nearest2 - refined1).
// Nearest gathered straight from raw partial (L2-hot).
__global__ __launch_bounds__(256) void update_kernel(
    const float* __restrict__ refined1,
    const float* __restrict__ partial,
    const float* __restrict__ md2,
    const int*   __restrict__ idx2,
    const float* __restrict__ bmax2,   // [NBLK]
    float* __restrict__ out)
{
    const int t = blockIdx.x * 256 + threadIdx.x;
    const int b = t >> 13;
    const int lane = threadIdx.x & 63;
    float v = bmax2[(b << 5) + (lane & 31)];
    #pragma unroll
    for (int o = 32; o > 0; o >>= 1) v = fmaxf(v, __shfl_down(v, o, 64));
    const float maxv = __shfl(v, 0, 64);
    const float md = md2[t];
    const int   id = idx2[t];
    const float alpha = BASE_ALPHA * (2.0f - md / (maxv + EPS));
    const float* nbp = partial + 3u * (unsigned)((b << 11) + id);
    const float nbx = nbp[0], nby = nbp[1], nbz = nbp[2];
    const float* p = refined1 + 3u * (unsigned)t;
    const float px = p[0], py = p[1], pz = p[2];
    float* o = out + 3u * (unsigned)t;
    o[0] = fmaf(alpha, nbx - px, px);
    o[1] = fmaf(alpha, nby - py, py);
    o[2] = fmaf(alpha, nbz - pz, pz);
}

extern "C" void kernel_launch(void* const* d_in, const int* in_sizes, int n_in,
                              void* d_out, int out_size, void* d_ws, size_t ws_size,
                              hipStream_t stream) {
    const float* pred    = (const float*)d_in[0];   // [8,8192,3] fp32
    const float* partial = (const float*)d_in[1];   // [8,2048,3] fp32
    float* out = (float*)d_out;

    char* ws = (char*)d_ws;
    float* ref1  = (float*)ws;                 // 768 KB
    float* md1   = (float*)(ws + 786432);      // 256 KB
    int*   idx1  = (int*)(ws + 1048576);       // 256 KB
    float* bmax1 = (float*)(ws + 1310720);     // 1 KB
    float* bmax2 = bmax1 + NBLK;               // 1 KB

    // Iter 1 NN: pred -> md1/idx1/bmax1 (tile built in-block)
    nn_kernel<false><<<NBLK, 1024, 0, stream>>>(
        pred, partial, nullptr, nullptr, nullptr, nullptr, md1, idx1, bmax1);

    // Iter 1 update fused into iter 2 NN: writes ref1, overwrites md1/idx1.
    nn_kernel<true><<<NBLK, 1024, 0, stream>>>(
        pred, partial, md1, idx1, bmax1, ref1, md1, idx1, bmax2);

    // Iter 2 update: ref1 -> out
    update_kernel<<<NPTS / 256, 256, 0, stream>>>(ref1, partial, md1, idx1, bmax2, out);
}

// Round 6
// 95.788 us; speedup vs baseline: 1.0146x; 1.0146x over previous
//
#include <hip/hip_runtime.h>
#include <math.h>

#define BATCH 8
#define NPRED 8192
#define MPART 2048
#define NPTS  (BATCH * NPRED)      // 65536 queries
#define QPL   4                    // queries per lane
#define SPLIT 16                   // 16 waves = 16 M-splits per block
#define PTS_PER_SPLIT (MPART / SPLIT)   // 128
#define GPS   (PTS_PER_SPLIT / 4)       // 32 groups of 4 points per split
#define QPB   256                  // queries per block (4 qpl * 64 lanes)
#define NBLK  (NPTS / QPB)         // 256 blocks (1 per CU)
#define BASE_ALPHA 0.05f
#define EPS 1e-6f

__device__ __forceinline__ unsigned long long shflx_u64(unsigned long long v, int m) {
    unsigned lo = (unsigned)v, hi = (unsigned)(v >> 32);
    lo = (unsigned)__shfl_xor((int)lo, m, 64);
    hi = (unsigned)__shfl_xor((int)hi, m, 64);
    return ((unsigned long long)hi << 32) | lo;
}

// Block = 1024 threads = 16 waves. Wave w scans M-split w (128 pts) for the
// block's 256 queries (4 per lane).
// Tile build: each thread reads its 2 points (12 B each) DIRECTLY from global
// (L2/L3-hot; 192 KB unique) and writes the grouped-SoA P' tile in LDS with
// FP ops identical to the original prep_kernel — r4's 24 KB LDS staging
// roundtrip and one barrier are gone.
// Scan: 2-deep register prefetch over broadcast ds_read_b128 (proven r0/r4
// mechanism; readlane/s_load variants measured slower in r1/r3).
// Grouped argmin: loop tracks (group-min, group-id); epilogue recomputes the
// winning group's 4 dots with IDENTICAL fp ops (bit-exact) to recover the
// element index; strict '<' + lowest-c tie-break = first-occurrence.
// Keys land in the virgin lk scratch (no pre-write barrier); merge uses all
// 16 waves (u64 min is commutative -> bit-identical to serial merge).
// FUSE: previous iteration's blend after the tile barrier; nearest gathered
// from the LDS tile via exact -0.5f*(-2x) reconstruction (r4-proven).
template <bool FUSE>
__global__ __launch_bounds__(1024) void nn_kernel(
    const float* __restrict__ src,      // [B,N,3] base positions
    const float* __restrict__ partial,  // [B,M,3] raw partial
    const float* md_in, const int* idx_in,   // FUSE only (alias outputs)
    const float* __restrict__ bmax_in,  // [NBLK] per-block max from prev pass
    float* __restrict__ refined_out,    // [B,N,3] (FUSE)
    float* md_out, int* idx_out,        // [B*N]
    float* __restrict__ bmax_out)       // [NBLK]
{
    __shared__ float4 tileP[2048];                 // 32 KB grouped-SoA P'
    __shared__ unsigned long long lk[SPLIT * QPB]; // 32 KB key buffer
    __shared__ float smax[SPLIT];

    const int qb   = blockIdx.x;
    const int b    = qb >> 5;               // 32 blocks per batch
    const int tid  = threadIdx.x;
    const int wave = tid >> 6, lane = tid & 63;
    const int split = wave;

    // ---- read this thread's 2 partial points straight from global ----
    const float* pbase = partial + (size_t)b * MPART * 3;
    float pxyz[2][3];
    #pragma unroll
    for (int k = 0; k < 2; ++k) {
        const int m = tid + (k << 10);
        const float* p = pbase + 3u * (unsigned)m;
        pxyz[k][0] = p[0]; pxyz[k][1] = p[1]; pxyz[k][2] = p[2];
    }

    // ---- query prologue (global-only part; overlaps the point loads) ----
    float axq[QPL], ayq[QPL], azq[QPL], a2q[QPL];
    float alpha_[QPL]; int id_[QPL];
    if (FUSE) {
        float v = bmax_in[(b << 5) + (lane & 31)];
        #pragma unroll
        for (int o = 32; o > 0; o >>= 1) v = fmaxf(v, __shfl_down(v, o, 64));
        const float maxv = __shfl(v, 0, 64);
        #pragma unroll
        for (int j = 0; j < QPL; ++j) {
            const int t = (qb << 8) + (j << 6) + lane;
            const float md = md_in[t];
            id_[j]    = idx_in[t];
            alpha_[j] = BASE_ALPHA * (2.0f - md / (maxv + EPS));
            const float* p = src + 3u * (unsigned)t;
            axq[j] = p[0]; ayq[j] = p[1]; azq[j] = p[2];
        }
    } else {
        #pragma unroll
        for (int j = 0; j < QPL; ++j) {
            const int t = (qb << 8) + (j << 6) + lane;
            const float* p = src + 3u * (unsigned)t;
            axq[j] = p[0]; ayq[j] = p[1]; azq[j] = p[2];
        }
    }

    // ---- build grouped-SoA P' tile (identical FP ops to old prep_kernel) --
    {
        float* tpf = (float*)tileP;
        #pragma unroll
        for (int k = 0; k < 2; ++k) {
            const int m = tid + (k << 10);
            const float x = pxyz[k][0], y = pxyz[k][1], z = pxyz[k][2];
            const int g = m >> 2, c = m & 3;
            float* basep = tpf + g * 16 + c;
            basep[0]  = -2.0f * x;
            basep[4]  = -2.0f * y;
            basep[8]  = -2.0f * z;
            basep[12] = fmaf(x, x, fmaf(y, y, z * z));
        }
    }
    __syncthreads();   // tile ready

    // ---- FUSE blend (nearest from tile: -0.5f*(-2x) == x bit-exactly) ----
    const float* tpf = (const float*)tileP;
    if (FUSE) {
        #pragma unroll
        for (int j = 0; j < QPL; ++j) {
            const int g = id_[j] >> 2, c = id_[j] & 3;
            const float nbx = -0.5f * tpf[g * 16 + c];
            const float nby = -0.5f * tpf[g * 16 + 4 + c];
            const float nbz = -0.5f * tpf[g * 16 + 8 + c];
            const float px = axq[j], py = ayq[j], pz = azq[j];
            axq[j] = fmaf(alpha_[j], nbx - px, px);
            ayq[j] = fmaf(alpha_[j], nby - py, py);
            azq[j] = fmaf(alpha_[j], nbz - pz, pz);
            if (split == 0) {               // one copy of refined-1 to ws
                const int t = (qb << 8) + (j << 6) + lane;
                float* o = refined_out + 3u * (unsigned)t;
                o[0] = axq[j]; o[1] = ayq[j]; o[2] = azq[j];
            }
        }
    }
    #pragma unroll
    for (int j = 0; j < QPL; ++j)
        a2q[j] = fmaf(axq[j], axq[j], fmaf(ayq[j], ayq[j], azq[j] * azq[j]));

    // ---- scan: 2-deep register prefetch over broadcast b128 reads ----
    const float4* wp = tileP + split * (GPS * 4);
    float best[QPL]; int bg[QPL];
    #pragma unroll
    for (int j = 0; j < QPL; ++j) { best[j] = 1e30f; bg[j] = 0; }

    auto step = [&](int i, const float4& X, const float4& Y,
                    const float4& Z, const float4& W) {
        #pragma unroll
        for (int j = 0; j < QPL; ++j) {
            const float ax = axq[j], ay = ayq[j], az = azq[j];
            const float d0 = fmaf(Z.x, az, fmaf(Y.x, ay, X.x * ax)) + W.x;
            const float d1 = fmaf(Z.y, az, fmaf(Y.y, ay, X.y * ax)) + W.y;
            const float d2 = fmaf(Z.z, az, fmaf(Y.z, ay, X.z * ax)) + W.z;
            const float d3 = fmaf(Z.w, az, fmaf(Y.w, ay, X.w * ax)) + W.w;
            const float gm = fminf(fminf(fminf(d0, d1), d2), d3);
            if (gm < best[j]) bg[j] = i;       // strict <: earliest group wins
            best[j] = fminf(best[j], gm);
        }
    };

    float4 Xc = wp[0], Yc = wp[1], Zc = wp[2], Wc = wp[3];
    #pragma unroll 4
    for (int i = 0; i < GPS - 1; ++i) {
        const float4 Xn = wp[4 * i + 4];
        const float4 Yn = wp[4 * i + 5];
        const float4 Zn = wp[4 * i + 6];
        const float4 Wn = wp[4 * i + 7];
        step(i, Xc, Yc, Zc, Wc);
        Xc = Xn; Yc = Yn; Zc = Zn; Wc = Wn;
    }
    step(GPS - 1, Xc, Yc, Zc, Wc);

    // ---- epilogue: bit-exact recompute of winning group -> element index --
    unsigned long long key[QPL];
    #pragma unroll
    for (int j = 0; j < QPL; ++j) {
        const int gi = bg[j];
        const float4 X = wp[4 * gi + 0];
        const float4 Y = wp[4 * gi + 1];
        const float4 Z = wp[4 * gi + 2];
        const float4 W = wp[4 * gi + 3];
        const float ax = axq[j], ay = ayq[j], az = azq[j];
        const float d0 = fmaf(Z.x, az, fmaf(Y.x, ay, X.x * ax)) + W.x;
        const float d1 = fmaf(Z.y, az, fmaf(Y.y, ay, X.y * ax)) + W.y;
        const float d2 = fmaf(Z.z, az, fmaf(Y.z, ay, X.z * ax)) + W.z;
        const float bv = best[j];
        int c;
        if      (d0 == bv) c = 0;
        else if (d1 == bv) c = 1;
        else if (d2 == bv) c = 2;
        else               c = 3;
        const int m = (split << 7) + (gi << 2) + c;   // index within batch
        const float dd = fmaxf(bv + a2q[j], 0.0f);    // nonneg -> uint-ordered
        key[j] = ((unsigned long long)__float_as_uint(dd) << 32) | (unsigned)m;
    }

    // lk is virgin up to here: no pre-write barrier needed.
    #pragma unroll
    for (int j = 0; j < QPL; ++j)
        lk[split * QPB + (j << 6) + lane] = key[j];
    __syncthreads();

    // ---- merge across splits, all 16 waves; u64 min == lexicographic ----
    {
        const int q  = (wave << 4) + (lane & 15);   // this lane's query
        const int s0 = (lane >> 4) << 2;            // its 4-split slice
        unsigned long long kk = lk[s0 * QPB + q];
        #pragma unroll
        for (int s = 1; s < 4; ++s) {
            const unsigned long long k = lk[(s0 + s) * QPB + q];
            if (k < kk) kk = k;
        }
        unsigned long long o = shflx_u64(kk, 16);
        if (o < kk) kk = o;
        o = shflx_u64(kk, 32);
        if (o < kk) kk = o;
        const float md = sqrtf(__uint_as_float((unsigned)(kk >> 32)));
        if (lane < 16) {
            const int t2 = (qb << 8) + q;
            md_out[t2]  = md;
            idx_out[t2] = (int)(kk & 0xffffffffu);
        }
        float w = md;
        #pragma unroll
        for (int o2 = 8; o2 > 0; o2 >>= 1) w = fmaxf(w, __shfl_xor(w, o2, 64));
        if (lane == 0) smax[wave] = w;
    }
    __syncthreads();
    if (tid == 0) {
        float m0 = smax[0];
        #pragma unroll
        for (int s = 1; s < SPLIT; ++s) m0 = fmaxf(m0, smax[s]);
        bmax_out[qb] = m0;
    }
}

// Final blend: out = refined1 + alpha2*(nearest2 - refined1).
// Nearest gathered straight from raw partial (L2-hot).
__global__ __launch_bounds__(256) void update_kernel(
    const float* __restrict__ refined1,
    const float* __restrict__ partial,
    const float* __restrict__ md2,
    const int*   __restrict__ idx2,
    const float* __restrict__ bmax2,   // [NBLK]
    float* __restrict__ out)
{
    const int t = blockIdx.x * 256 + threadIdx.x;
    const int b = t >> 13;
    const int lane = threadIdx.x & 63;
    float v = bmax2[(b << 5) + (lane & 31)];
    #pragma unroll
    for (int o = 32; o > 0; o >>= 1) v = fmaxf(v, __shfl_down(v, o, 64));
    const float maxv = __shfl(v, 0, 64);
    const float md = md2[t];
    const int   id = idx2[t];
    const float alpha = BASE_ALPHA * (2.0f - md / (maxv + EPS));
    const float* nbp = partial + 3u * (unsigned)((b << 11) + id);
    const float nbx = nbp[0], nby = nbp[1], nbz = nbp[2];
    const float* p = refined1 + 3u * (unsigned)t;
    const float px = p[0], py = p[1], pz = p[2];
    float* o = out + 3u * (unsigned)t;
    o[0] = fmaf(alpha, nbx - px, px);
    o[1] = fmaf(alpha, nby - py, py);
    o[2] = fmaf(alpha, nbz - pz, pz);
}

extern "C" void kernel_launch(void* const* d_in, const int* in_sizes, int n_in,
                              void* d_out, int out_size, void* d_ws, size_t ws_size,
                              hipStream_t stream) {
    const float* pred    = (const float*)d_in[0];   // [8,8192,3] fp32
    const float* partial = (const float*)d_in[1];   // [8,2048,3] fp32
    float* out = (float*)d_out;

    char* ws = (char*)d_ws;
    float* ref1  = (float*)ws;                 // 768 KB
    float* md1   = (float*)(ws + 786432);      // 256 KB
    int*   idx1  = (int*)(ws + 1048576);       // 256 KB
    float* bmax1 = (float*)(ws + 1310720);     // 1 KB
    float* bmax2 = bmax1 + NBLK;               // 1 KB

    // Iter 1 NN: pred -> md1/idx1/bmax1 (tile built in-block from global)
    nn_kernel<false><<<NBLK, 1024, 0, stream>>>(
        pred, partial, nullptr, nullptr, nullptr, nullptr, md1, idx1, bmax1);

    // Iter 1 update fused into iter 2 NN: writes ref1, overwrites md1/idx1.
    nn_kernel<true><<<NBLK, 1024, 0, stream>>>(
        pred, partial, md1, idx1, bmax1, ref1, md1, idx1, bmax2);

    // Iter 2 update: ref1 -> out
    update_kernel<<<NPTS / 256, 256, 0, stream>>>(ref1, partial, md1, idx1, bmax2, out);
}